// Round 7
// baseline (680.197 us; speedup 1.0000x reference)
//
#include <hip/hip_runtime.h>
#include <cstdint>
#include <cstddef>

// Problem constants (B,N,M,D fixed by the reference setup_inputs)
#define BB 8
#define NPTS 2048
#define DIM 64
#define CK 128    // Q cols staged per chunk (per column-half pipeline)

typedef _Float16 f16x8 __attribute__((ext_vector_type(8)));
typedef float f32x4 __attribute__((ext_vector_type(4)));

// eps schedule: DIAMETER^2 * 0.25^k down to blur^2 = 0.0025 (9 entries)
static const float EPS_H[9] = {100.0f, 25.0f, 6.25f, 1.5625f, 0.390625f,
                               0.09765625f, 0.0244140625f, 0.006103515625f,
                               0.0025f};

#if __has_builtin(__builtin_amdgcn_exp2f)
static __device__ __forceinline__ float fexp2(float x) {
  return __builtin_amdgcn_exp2f(x);
}
#else
static __device__ __forceinline__ float fexp2(float x) {
  float r;
  asm("v_exp_f32 %0, %1" : "=v"(r) : "v"(x));
  return r;
}
#endif

static __device__ __forceinline__ f32x4 vmax4(f32x4 a, f32x4 b) {
  f32x4 r;
  #pragma unroll
  for (int i = 0; i < 4; ++i) r[i] = fmaxf(a[i], b[i]);
  return r;
}

static __device__ __forceinline__ f32x4 vexp2_4(f32x4 a) {
  f32x4 r;
  #pragma unroll
  for (int i = 0; i < 4; ++i) r[i] = fexp2(a[i]);
  return r;
}

static __device__ __forceinline__ void gload_lds16(const void* g, void* l) {
  __builtin_amdgcn_global_load_lds(
      (const __attribute__((address_space(1))) void*)g,
      (__attribute__((address_space(3))) void*)l, 16, 0, 0);
}

// A pair of softmin tasks sharing the same Q (reduce-side) points, log-weights
// and |q|^2; only the fed-back potential / output side differ.
struct PTask {
  const _Float16* Q;   // [B,2048,64] shared reduce-side points
  const float* lw;     // [B,2048] shared log weights
  const float* q2;     // [B,2048] shared |q|^2
  const _Float16* P0;  // task0 row-side points
  const float* pot0;   // task0 potential on Q side (nullptr at init)
  const float* psq0;   // task0 |p|^2
  const float* oldf0;  // task0 averaging input (nullptr = none)
  float* out0;
  const _Float16* P1;  // task1 row-side points
  const float* pot1;
  const float* psq1;
  const float* oldf1;
  float* out1;
};

// ---------------- prep kernels ----------------

__global__ __launch_bounds__(256) void norm_weights_k(
    const float* __restrict__ w, float* __restrict__ aout,
    float* __restrict__ logout, int n) {
  int b = blockIdx.x;
  const float* wb = w + (size_t)b * n;
  __shared__ float red[256];
  float s = 0.f;
  for (int i = threadIdx.x; i < n; i += 256) s += wb[i];
  red[threadIdx.x] = s;
  __syncthreads();
  for (int st = 128; st > 0; st >>= 1) {
    if (threadIdx.x < st) red[threadIdx.x] += red[threadIdx.x + st];
    __syncthreads();
  }
  float mass = red[0];
  if (mass == 0.f) mass = 1.f;
  float inv = 1.f / mass;
  for (int i = threadIdx.x; i < n; i += 256) {
    float av = wb[i] * inv;
    aout[(size_t)b * n + i] = av;
    logout[(size_t)b * n + i] = logf(av);
  }
}

// squared norm of each D=64 row + fp16 conversion: one wave per row
__global__ __launch_bounds__(256) void sqnorm_cvt_k(
    const float* __restrict__ X, float* __restrict__ sq,
    _Float16* __restrict__ Xh, int rows) {
  int row = blockIdx.x * 4 + (threadIdx.x >> 6);
  int lane = threadIdx.x & 63;
  if (row >= rows) return;
  float v = X[(size_t)row * DIM + lane];
  Xh[(size_t)row * DIM + lane] = (_Float16)v;
  float s = v * v;
  #pragma unroll
  for (int off = 32; off > 0; off >>= 1) s += __shfl_xor(s, off);
  if (lane == 0) sq[row] = s;
}

// ---------------- fused cost+softmin (paired tasks, wave m-split) ----------
// For each task t in the pair:
//   out_t[b,r] = -eps*ln2*log2( sum_m 2^{hq_t[m] + dot(Pt_r,Q_m)*ie2} )
//               + 0.5*psq_t[r]   (then optional 0.5*(oldf+.) averaging)
// hq_t[m] = lw[m]*log2e + pot_t[m]*ie2 - 0.5*q2[m]*ie2.
// Block = 8 waves (512 thr). Waves 0-3 sweep cols 0-1023, waves 4-7 sweep
// 1024-2047 (separate double-buffered LDS staging pipelines). Each wave owns
// 16 P-rows and computes BOTH tasks from one staged B-fragment read.
// Column-half partial (mx,sm) merged in LDS at the end.
__global__ __launch_bounds__(512, 4) void fused_softmin_k(
    PTask u0, PTask u1, float ie2, float neg_eps_ln2) {
  __shared__ __align__(16) _Float16 qb[2][2][CK * DIM];  // [half][dbuf] 64 KB
  __shared__ float cmxs[2][2][64];                       // [task][half][row]
  __shared__ float csms[2][2][64];
  PTask U = blockIdx.z ? u1 : u0;
  const int b = blockIdx.y;
  const int tid = threadIdx.x;
  const int lane = tid & 63, wave = tid >> 6;
  const int half = wave >> 2, wsub = wave & 3;
  const float LOG2E = 1.4426950408889634f;

  const _Float16* Qb = U.Q + (size_t)b * NPTS * DIM;
  const float* lwb = U.lw + (size_t)b * NPTS;
  const float* q2b = U.q2 + (size_t)b * NPTS;
  const float* pt0 = U.pot0 ? U.pot0 + (size_t)b * NPTS : nullptr;
  const float* pt1 = U.pot1 ? U.pot1 + (size_t)b * NPTS : nullptr;

  // stage chunk c of this wave's column half -> qb[half][buf].
  // Linear LDS dest, inverse-swizzled global source (rule #21): granule gid
  // holds Q[m0+gid/8][8 halfs of k-granule (gid%8)^((gid/8)&7)].
  auto stage = [&](int buf, int c) {
    int m0 = half * (NPTS / 2) + c * CK;
    #pragma unroll
    for (int r = 0; r < 4; ++r) {
      int gbase = r * 256 + wsub * 64;
      int gid = gbase + lane;
      int row = gid >> 3;
      int kg = (gid & 7) ^ (row & 7);
      const _Float16* src = Qb + (size_t)(m0 + row) * DIM + kg * 8;
      _Float16* dst = &qb[half][buf][(size_t)gbase * 8];  // wave-uniform base
      gload_lds16(src, dst);
    }
  };

  const int fr = lane & 15;        // MFMA row/col index within fragment
  const int g0 = lane >> 4;        // k-granule group (0..3)
  const int r0 = blockIdx.x * 64 + wsub * 16;
  const _Float16* P0b = U.P0 + ((size_t)b * NPTS + r0) * DIM;
  const _Float16* P1b = U.P1 + ((size_t)b * NPTS + r0) * DIM;
  f16x8 a00 = *(const f16x8*)(P0b + fr * DIM + g0 * 8);
  f16x8 a01 = *(const f16x8*)(P0b + fr * DIM + g0 * 8 + 32);
  f16x8 a10 = *(const f16x8*)(P1b + fr * DIM + g0 * 8);
  f16x8 a11 = *(const f16x8*)(P1b + fr * DIM + g0 * 8 + 32);

  f32x4 mx0 = {-3.0e38f, -3.0e38f, -3.0e38f, -3.0e38f};
  f32x4 mx1 = mx0;
  f32x4 sm0 = {0.f, 0.f, 0.f, 0.f};
  f32x4 sm1 = sm0;

  stage(0, 0);
  __syncthreads();  // chunk-0 staged (vmcnt drained by barrier semantics)

  for (int c = 0; c < NPTS / 2 / CK; ++c) {
    int cur = c & 1;
    if (c + 1 < NPTS / 2 / CK) stage(cur ^ 1, c + 1);
    const int m0 = half * (NPTS / 2) + c * CK;
    const char* qbase = (const char*)&qb[half][cur][0];

    #pragma unroll
    for (int sh = 0; sh < 2; ++sh) {
      float hs0[4], hs1[4];
      #pragma unroll
      for (int s4 = 0; s4 < 4; ++s4) {
        int m = m0 + (sh * 4 + s4) * 16 + fr;
        float hb = fmaf(lwb[m], LOG2E, -0.5f * q2b[m] * ie2);
        hs0[s4] = pt0 ? fmaf(pt0[m], ie2, hb) : hb;
        hs1[s4] = pt1 ? fmaf(pt1[m], ie2, hb) : hb;
      }
      f32x4 v0[4], v1[4];
      f32x4 c0 = mx0, c1 = mx1;
      #pragma unroll
      for (int s4 = 0; s4 < 4; ++s4) {
        int row = (sh * 4 + s4) * 16 + fr;
        int byte0 = row * 128 + ((g0 ^ (row & 7)) << 4);
        int byte1 = row * 128 + (((g0 + 4) ^ (row & 7)) << 4);
        f16x8 b0 = *(const f16x8*)(qbase + byte0);
        f16x8 b1 = *(const f16x8*)(qbase + byte1);
        f32x4 z = {0.f, 0.f, 0.f, 0.f};
        f32x4 t0 = __builtin_amdgcn_mfma_f32_16x16x32_f16(a00, b0, z, 0, 0, 0);
        f32x4 acc0 = __builtin_amdgcn_mfma_f32_16x16x32_f16(a01, b1, t0, 0, 0, 0);
        f32x4 t1 = __builtin_amdgcn_mfma_f32_16x16x32_f16(a10, b0, z, 0, 0, 0);
        f32x4 acc1 = __builtin_amdgcn_mfma_f32_16x16x32_f16(a11, b1, t1, 0, 0, 0);
        v0[s4] = acc0 * ie2 + hs0[s4];
        v1[s4] = acc1 * ie2 + hs1[s4];
        c0 = vmax4(c0, v0[s4]);
        c1 = vmax4(c1, v1[s4]);
      }
      f32x4 e0 = vexp2_4(v0[0] - c0) + vexp2_4(v0[1] - c0);
      e0 += vexp2_4(v0[2] - c0) + vexp2_4(v0[3] - c0);
      sm0 = sm0 * vexp2_4(mx0 - c0) + e0;
      mx0 = c0;
      f32x4 e1 = vexp2_4(v1[0] - c1) + vexp2_4(v1[1] - c1);
      e1 += vexp2_4(v1[2] - c1) + vexp2_4(v1[3] - c1);
      sm1 = sm1 * vexp2_4(mx1 - c1) + e1;
      mx1 = c1;
    }
    __syncthreads();  // staged next chunk ready + buffer-swap safety
  }

  // reduce (mx,sm) over the 16 fr lanes (cols) of each row group, both tasks
  #pragma unroll
  for (int off = 1; off < 16; off <<= 1) {
    #pragma unroll
    for (int q = 0; q < 4; ++q) {
      {
        float omx = __shfl_xor(mx0[q], off);
        float osm = __shfl_xor(sm0[q], off);
        float nm = fmaxf(mx0[q], omx);
        sm0[q] = sm0[q] * fexp2(mx0[q] - nm) + osm * fexp2(omx - nm);
        mx0[q] = nm;
      }
      {
        float omx = __shfl_xor(mx1[q], off);
        float osm = __shfl_xor(sm1[q], off);
        float nm = fmaxf(mx1[q], omx);
        sm1[q] = sm1[q] * fexp2(mx1[q] - nm) + osm * fexp2(omx - nm);
        mx1[q] = nm;
      }
    }
  }
  if (fr == 0) {
    #pragma unroll
    for (int q = 0; q < 4; ++q) {
      int rl = wsub * 16 + g0 * 4 + q;
      cmxs[0][half][rl] = mx0[q];
      csms[0][half][rl] = sm0[q];
      cmxs[1][half][rl] = mx1[q];
      csms[1][half][rl] = sm1[q];
    }
  }
  __syncthreads();

  // merge column halves + epilogue: 128 threads (task = tid>>6, row = tid&63)
  if (tid < 128) {
    int task = tid >> 6;
    int rl = tid & 63;
    float ma = cmxs[task][0][rl], mb = cmxs[task][1][rl];
    float nm = fmaxf(ma, mb);
    float ss = csms[task][0][rl] * fexp2(ma - nm) +
               csms[task][1][rl] * fexp2(mb - nm);
    size_t oi = (size_t)b * NPTS + blockIdx.x * 64 + rl;
    const float* psq = task ? U.psq1 : U.psq0;
    const float* oldf = task ? U.oldf1 : U.oldf0;
    float* outp = task ? U.out1 : U.out0;
    float f = neg_eps_ln2 * (__log2f(ss) + nm) + 0.5f * psq[oi];
    if (oldf) f = 0.5f * (oldf[oi] + f);
    outp[oi] = f;
  }
}

// ---------------- epilogue (two-stage) ----------------
__global__ __launch_bounds__(256) void loss_part_k(
    const float* __restrict__ aW, const float* __restrict__ f_fin,
    const float* __restrict__ f_aa, const float* __restrict__ bW,
    const float* __restrict__ g_fin, const float* __restrict__ g_bb,
    float* __restrict__ part) {
  __shared__ float red[256];
  int i0 = blockIdx.x * 256 + threadIdx.x;
  float s = 0.f;
  for (int i = i0; i < BB * NPTS; i += 64 * 256)
    s += aW[i] * (f_fin[i] - f_aa[i]) + bW[i] * (g_fin[i] - g_bb[i]);
  red[threadIdx.x] = s;
  __syncthreads();
  for (int st = 128; st > 0; st >>= 1) {
    if (threadIdx.x < st) red[threadIdx.x] += red[threadIdx.x + st];
    __syncthreads();
  }
  if (threadIdx.x == 0) part[blockIdx.x] = red[0];
}

__global__ __launch_bounds__(64) void loss_fin_k(const float* __restrict__ part,
                                                 float* __restrict__ out) {
  float s = part[threadIdx.x];
  #pragma unroll
  for (int off = 32; off > 0; off >>= 1) s += __shfl_xor(s, off);
  if (threadIdx.x == 0) out[0] = s * (1.f / BB);
}

__global__ void write_val_k(float* out, float v) { out[0] = v; }

// ---------------- host ----------------

extern "C" void kernel_launch(void* const* d_in, const int* in_sizes, int n_in,
                              void* d_out, int out_size, void* d_ws,
                              size_t ws_size, hipStream_t stream) {
  (void)in_sizes; (void)n_in; (void)out_size;
  const float* X = (const float*)d_in[0];   // [B,N,D]
  const float* Y = (const float*)d_in[1];   // [B,M,D]
  const float* W1 = (const float*)d_in[2];  // [B,N]
  const float* W2 = (const float*)d_in[3];  // [B,M]
  float* out = (float*)d_out;

  char* base = (char*)d_ws;
  size_t off = 0;
  auto alloc_b = [&](size_t bytes) {
    void* r = base + off;
    off += (bytes + 255) & ~(size_t)255;
    return r;
  };
  const size_t nP = (size_t)BB * NPTS;
  _Float16* Xh = (_Float16*)alloc_b(nP * DIM * 2);
  _Float16* Yh = (_Float16*)alloc_b(nP * DIM * 2);
  float* x2 = (float*)alloc_b(nP * 4);
  float* y2 = (float*)alloc_b(nP * 4);
  float* aW = (float*)alloc_b(nP * 4);
  float* bW = (float*)alloc_b(nP * 4);
  float* la = (float*)alloc_b(nP * 4);
  float* lb = (float*)alloc_b(nP * 4);
  float* fba[2] = {(float*)alloc_b(nP * 4), (float*)alloc_b(nP * 4)};
  float* gab[2] = {(float*)alloc_b(nP * 4), (float*)alloc_b(nP * 4)};
  float* faa[2] = {(float*)alloc_b(nP * 4), (float*)alloc_b(nP * 4)};
  float* gbb[2] = {(float*)alloc_b(nP * 4), (float*)alloc_b(nP * 4)};
  float* part = (float*)alloc_b(64 * 4);
  if (ws_size < off) {
    write_val_k<<<1, 1, 0, stream>>>(out, -(float)(ws_size >> 20));
    return;
  }

  // prep
  norm_weights_k<<<BB, 256, 0, stream>>>(W1, aW, la, NPTS);
  norm_weights_k<<<BB, 256, 0, stream>>>(W2, bW, lb, NPTS);
  sqnorm_cvt_k<<<BB * NPTS / 4, 256, 0, stream>>>(X, x2, Xh, BB * NPTS);
  sqnorm_cvt_k<<<BB * NPTS / 4, 256, 0, stream>>>(Y, y2, Yh, BB * NPTS);

  const float LN2 = 0.6931471805599453f;
  const float LOG2E = 1.4426950408889634f;
  dim3 fg(NPTS / 64, BB, 2);

  // pair0: {t0 = f_ba-type (P=Xh, out over X rows), t1 = g_bb (P=Yh)}, Q=Yh
  // pair1: {t0 = g_ab-type (P=Yh), t1 = f_aa (P=Xh)}, Q=Xh
  auto launch4 = [&](const float* potF, const float* oldF, float* outF,
                     const float* potG, const float* oldG, float* outG,
                     const float* potA, const float* oldA, float* outA,
                     const float* potBv, const float* oldBv, float* outBv,
                     float eps) {
    float ie2 = LOG2E / eps;
    float nel = -eps * LN2;
    PTask u0{Yh, lb, y2,
             Xh, potF, x2, oldF, outF,    // f_ba update
             Yh, potBv, y2, oldBv, outBv};  // g_bb update
    PTask u1{Xh, la, x2,
             Yh, potG, y2, oldG, outG,    // g_ab update
             Xh, potA, x2, oldA, outA};   // f_aa update
    fused_softmin_k<<<fg, 512, 0, stream>>>(u0, u1, ie2, nel);
  };

  // init at eps0 (no potential, no averaging)
  launch4(nullptr, nullptr, fba[0], nullptr, nullptr, gab[0],
          nullptr, nullptr, faa[0], nullptr, nullptr, gbb[0], EPS_H[0]);

  // annealing loop: symmetric averaged updates, double-buffered
  int cur = 0;
  for (int it = 0; it < 9; ++it) {
    int nxt = cur ^ 1;
    launch4(gab[cur], fba[cur], fba[nxt],
            fba[cur], gab[cur], gab[nxt],
            faa[cur], faa[cur], faa[nxt],
            gbb[cur], gbb[cur], gbb[nxt], EPS_H[it]);
    cur = nxt;
  }

  // final extrapolation at eps target (no averaging)
  {
    int nxt = cur ^ 1;
    launch4(gab[cur], nullptr, fba[nxt],
            fba[cur], nullptr, gab[nxt],
            faa[cur], nullptr, faa[nxt],
            gbb[cur], nullptr, gbb[nxt], EPS_H[8]);
    loss_part_k<<<64, 256, 0, stream>>>(aW, fba[nxt], faa[nxt], bW, gab[nxt],
                                        gbb[nxt], part);
    loss_fin_k<<<1, 64, 0, stream>>>(part, out);
  }
}

// Round 8
// 502.645 us; speedup vs baseline: 1.3532x; 1.3532x over previous
//
#include <hip/hip_runtime.h>
#include <cstdint>
#include <cstddef>

// Problem constants (B,N,M,D fixed by the reference setup_inputs)
#define BB 8
#define NPTS 2048
#define DIM 64
#define CK 64     // Q cols staged per chunk
#define NC (NPTS / CK)
#define BROWS 64  // P rows per block (4 waves x 16 rows)

typedef _Float16 f16x8 __attribute__((ext_vector_type(8)));
typedef float f32x4 __attribute__((ext_vector_type(4)));

// eps schedule: DIAMETER^2 * 0.25^k down to blur^2 = 0.0025 (9 entries)
static const float EPS_H[9] = {100.0f, 25.0f, 6.25f, 1.5625f, 0.390625f,
                               0.09765625f, 0.0244140625f, 0.006103515625f,
                               0.0025f};

#if __has_builtin(__builtin_amdgcn_exp2f)
static __device__ __forceinline__ float fexp2(float x) {
  return __builtin_amdgcn_exp2f(x);
}
#else
static __device__ __forceinline__ float fexp2(float x) {
  float r;
  asm("v_exp_f32 %0, %1" : "=v"(r) : "v"(x));
  return r;
}
#endif

static __device__ __forceinline__ f32x4 vmax4(f32x4 a, f32x4 b) {
  f32x4 r;
  #pragma unroll
  for (int i = 0; i < 4; ++i) r[i] = fmaxf(a[i], b[i]);
  return r;
}

static __device__ __forceinline__ f32x4 vexp2_4(f32x4 a) {
  f32x4 r;
  #pragma unroll
  for (int i = 0; i < 4; ++i) r[i] = fexp2(a[i]);
  return r;
}

static __device__ __forceinline__ void gload_lds16(const void* g, void* l) {
  __builtin_amdgcn_global_load_lds(
      (const __attribute__((address_space(1))) void*)g,
      (__attribute__((address_space(3))) void*)l, 16, 0, 0);
}

struct SMTask {
  const _Float16* P;   // [B,2048,64] row-side points (output indexed by these)
  const _Float16* Q;   // [B,2048,64] reduce-side points
  const float* logw;   // [B,2048] log weights of Q side
  const float* pot;    // [B,2048] potential on Q side (nullptr at init)
  const float* qsq;    // [B,2048] |q|^2
  const float* psq;    // [B,2048] |p|^2
  const float* oldf;   // [B,2048] for 0.5*(old+new) averaging (nullptr = none)
  float* out;          // [B,2048]
};

// ---------------- prep kernels ----------------

__global__ __launch_bounds__(256) void norm_weights_k(
    const float* __restrict__ w, float* __restrict__ aout,
    float* __restrict__ logout, int n) {
  int b = blockIdx.x;
  const float* wb = w + (size_t)b * n;
  __shared__ float red[256];
  float s = 0.f;
  for (int i = threadIdx.x; i < n; i += 256) s += wb[i];
  red[threadIdx.x] = s;
  __syncthreads();
  for (int st = 128; st > 0; st >>= 1) {
    if (threadIdx.x < st) red[threadIdx.x] += red[threadIdx.x + st];
    __syncthreads();
  }
  float mass = red[0];
  if (mass == 0.f) mass = 1.f;
  float inv = 1.f / mass;
  for (int i = threadIdx.x; i < n; i += 256) {
    float av = wb[i] * inv;
    aout[(size_t)b * n + i] = av;
    logout[(size_t)b * n + i] = logf(av);
  }
}

// squared norm of each D=64 row + fp16 conversion: one wave per row
__global__ __launch_bounds__(256) void sqnorm_cvt_k(
    const float* __restrict__ X, float* __restrict__ sq,
    _Float16* __restrict__ Xh, int rows) {
  int row = blockIdx.x * 4 + (threadIdx.x >> 6);
  int lane = threadIdx.x & 63;
  if (row >= rows) return;
  float v = X[(size_t)row * DIM + lane];
  Xh[(size_t)row * DIM + lane] = (_Float16)v;
  float s = v * v;
  #pragma unroll
  for (int off = 32; off > 0; off >>= 1) s += __shfl_xor(s, off);
  if (lane == 0) sq[row] = s;
}

// ---------------- fused cost+softmin (LDS-staged, counted-vmcnt pipeline) --
// out[b,r] = -eps*ln2*( log2 sum_m 2^{ hq[m] + S[r,m]*ie2 } ) + 0.5*psq[r]
// S[r,m] = dot(P_r, Q_m) (f16 MFMA, fp32 acc)
// hq[m] = logw[m]*log2e + pot[m]*ie2 - 0.5*q2[m]*ie2,  ie2 = log2e/eps.
// Block = 4 waves x 16 P-rows; Q swept in 64-col LDS chunks, double-buffered
// via global_load_lds with COUNTED vmcnt (never 0 in loop) + raw s_barrier
// (no vmcnt drain at barriers — loads for chunk c+1 stay in flight).
__global__ __launch_bounds__(256, 4) void fused_softmin_k(
    SMTask t0, SMTask t1, SMTask t2, SMTask t3, float ie2, float neg_eps_ln2) {
  __shared__ float hq[NPTS];                         // 8 KB
  __shared__ __align__(16) _Float16 qb[2][CK * DIM]; // 2 x 8 KB
  SMTask T = (blockIdx.z == 0) ? t0
           : (blockIdx.z == 1) ? t1
           : (blockIdx.z == 2) ? t2 : t3;
  const int b = blockIdx.y;
  const int tid = threadIdx.x;
  const float LOG2E = 1.4426950408889634f;
  {
    const float* lw = T.logw + (size_t)b * NPTS;
    const float* q2 = T.qsq + (size_t)b * NPTS;
    const float* pt = T.pot ? T.pot + (size_t)b * NPTS : nullptr;
    for (int m = tid; m < NPTS; m += 256) {
      float h = fmaf(lw[m], LOG2E, -0.5f * q2[m] * ie2);
      if (pt) h = fmaf(pt[m], ie2, h);
      hq[m] = h;
    }
  }

  const int lane = tid & 63, wave = tid >> 6;
  const _Float16* Qb = T.Q + (size_t)b * NPTS * DIM;

  // stage chunk -> qb[buf]: linear LDS dest, inverse-swizzled global source
  // (rule #21). granule gid holds Q[m0+gid/8][8 halfs of k-granule
  // (gid%8)^((gid/8)&7)]. 2 global_load_lds instructions per wave per chunk.
  auto stage = [&](int buf, int chunk) {
    int m0 = chunk * CK;
    #pragma unroll
    for (int r = 0; r < 2; ++r) {
      int gbase = r * 256 + wave * 64;
      int gid = gbase + lane;
      int row = gid >> 3;
      int kg = (gid & 7) ^ (row & 7);
      const _Float16* src = Qb + (size_t)(m0 + row) * DIM + kg * 8;
      _Float16* dst = &qb[buf][(size_t)gbase * 8];  // wave-uniform base
      gload_lds16(src, dst);
    }
  };

  const int fr = lane & 15;        // MFMA row/col index within fragment
  const int g0 = lane >> 4;        // k-granule group (0..3)
  const int r0 = blockIdx.x * BROWS + wave * 16;
  const _Float16* Pb = T.P + ((size_t)b * NPTS + r0) * DIM;
  f16x8 a0 = *(const f16x8*)(Pb + fr * DIM + g0 * 8);
  f16x8 a1 = *(const f16x8*)(Pb + fr * DIM + g0 * 8 + 32);

  f32x4 mx4 = {-3.0e38f, -3.0e38f, -3.0e38f, -3.0e38f};
  f32x4 sm4 = {0.f, 0.f, 0.f, 0.f};

  auto compute = [&](int cur, int m0) {
    const char* qbase = (const char*)&qb[cur][0];
    f32x4 v4[4];
    f32x4 cmx = mx4;
    #pragma unroll
    for (int s = 0; s < 4; ++s) {
      int row = s * 16 + fr;
      int byte0 = row * 128 + ((g0 ^ (row & 7)) << 4);
      int byte1 = row * 128 + (((g0 + 4) ^ (row & 7)) << 4);
      f16x8 b0 = *(const f16x8*)(qbase + byte0);
      f16x8 b1 = *(const f16x8*)(qbase + byte1);
      float hs = hq[m0 + s * 16 + fr];
      f32x4 z = {0.f, 0.f, 0.f, 0.f};
      f32x4 t = __builtin_amdgcn_mfma_f32_16x16x32_f16(a0, b0, z, 0, 0, 0);
      f32x4 acc = __builtin_amdgcn_mfma_f32_16x16x32_f16(a1, b1, t, 0, 0, 0);
      v4[s] = acc * ie2 + hs;
      cmx = vmax4(cmx, v4[s]);
    }
    f32x4 resc = vexp2_4(mx4 - cmx);
    f32x4 esum = vexp2_4(v4[0] - cmx) + vexp2_4(v4[1] - cmx);
    esum += vexp2_4(v4[2] - cmx) + vexp2_4(v4[3] - cmx);
    sm4 = sm4 * resc + esum;
    mx4 = cmx;
  };

  stage(0, 0);
  __syncthreads();  // one full drain: hq visible + chunk-0 staged

  for (int c = 0; c < NC - 1; ++c) {
    int cur = c & 1;
    stage(cur ^ 1, c + 1);  // buffer consumed in iter c-1 (B2 certified)
    // wait my chunk-c loads (2 oldest); keep chunk-(c+1)'s 2 in flight
    asm volatile("s_waitcnt vmcnt(2)" ::: "memory");
    __builtin_amdgcn_sched_barrier(0);
    __builtin_amdgcn_s_barrier();  // B1: chunk c globally staged
    __builtin_amdgcn_sched_barrier(0);
    compute(cur, c * CK);
    __builtin_amdgcn_sched_barrier(0);
    __builtin_amdgcn_s_barrier();  // B2: all waves done reading qb[cur]
    __builtin_amdgcn_sched_barrier(0);
  }
  // peeled last chunk: drain remaining 2 loads (only time vmcnt hits 0)
  asm volatile("s_waitcnt vmcnt(0)" ::: "memory");
  __builtin_amdgcn_sched_barrier(0);
  __builtin_amdgcn_s_barrier();
  __builtin_amdgcn_sched_barrier(0);
  compute((NC - 1) & 1, (NC - 1) * CK);

  // reduce (mx,sm) over the 16 fr lanes (cols) of each row group
  #pragma unroll
  for (int off = 1; off < 16; off <<= 1) {
    #pragma unroll
    for (int q = 0; q < 4; ++q) {
      float omx = __shfl_xor(mx4[q], off);
      float osm = __shfl_xor(sm4[q], off);
      float nm = fmaxf(mx4[q], omx);
      sm4[q] = sm4[q] * fexp2(mx4[q] - nm) + osm * fexp2(omx - nm);
      mx4[q] = nm;
    }
  }
  if (fr == 0) {
    #pragma unroll
    for (int q = 0; q < 4; ++q) {
      int r = r0 + g0 * 4 + q;
      size_t oi = (size_t)b * NPTS + r;
      float f = neg_eps_ln2 * (__log2f(sm4[q]) + mx4[q]) + 0.5f * T.psq[oi];
      if (T.oldf) f = 0.5f * (T.oldf[oi] + f);
      T.out[oi] = f;
    }
  }
}

// ---------------- epilogue (two-stage) ----------------
__global__ __launch_bounds__(256) void loss_part_k(
    const float* __restrict__ aW, const float* __restrict__ f_fin,
    const float* __restrict__ f_aa, const float* __restrict__ bW,
    const float* __restrict__ g_fin, const float* __restrict__ g_bb,
    float* __restrict__ part) {
  __shared__ float red[256];
  int i0 = blockIdx.x * 256 + threadIdx.x;
  float s = 0.f;
  for (int i = i0; i < BB * NPTS; i += 64 * 256)
    s += aW[i] * (f_fin[i] - f_aa[i]) + bW[i] * (g_fin[i] - g_bb[i]);
  red[threadIdx.x] = s;
  __syncthreads();
  for (int st = 128; st > 0; st >>= 1) {
    if (threadIdx.x < st) red[threadIdx.x] += red[threadIdx.x + st];
    __syncthreads();
  }
  if (threadIdx.x == 0) part[blockIdx.x] = red[0];
}

__global__ __launch_bounds__(64) void loss_fin_k(const float* __restrict__ part,
                                                 float* __restrict__ out) {
  float s = part[threadIdx.x];
  #pragma unroll
  for (int off = 32; off > 0; off >>= 1) s += __shfl_xor(s, off);
  if (threadIdx.x == 0) out[0] = s * (1.f / BB);
}

__global__ void write_val_k(float* out, float v) { out[0] = v; }

// ---------------- host ----------------

extern "C" void kernel_launch(void* const* d_in, const int* in_sizes, int n_in,
                              void* d_out, int out_size, void* d_ws,
                              size_t ws_size, hipStream_t stream) {
  (void)in_sizes; (void)n_in; (void)out_size;
  const float* X = (const float*)d_in[0];   // [B,N,D]
  const float* Y = (const float*)d_in[1];   // [B,M,D]
  const float* W1 = (const float*)d_in[2];  // [B,N]
  const float* W2 = (const float*)d_in[3];  // [B,M]
  float* out = (float*)d_out;

  char* base = (char*)d_ws;
  size_t off = 0;
  auto alloc_b = [&](size_t bytes) {
    void* r = base + off;
    off += (bytes + 255) & ~(size_t)255;
    return r;
  };
  const size_t nP = (size_t)BB * NPTS;
  _Float16* Xh = (_Float16*)alloc_b(nP * DIM * 2);
  _Float16* Yh = (_Float16*)alloc_b(nP * DIM * 2);
  float* x2 = (float*)alloc_b(nP * 4);
  float* y2 = (float*)alloc_b(nP * 4);
  float* aW = (float*)alloc_b(nP * 4);
  float* bW = (float*)alloc_b(nP * 4);
  float* la = (float*)alloc_b(nP * 4);
  float* lb = (float*)alloc_b(nP * 4);
  float* fba[2] = {(float*)alloc_b(nP * 4), (float*)alloc_b(nP * 4)};
  float* gab[2] = {(float*)alloc_b(nP * 4), (float*)alloc_b(nP * 4)};
  float* faa[2] = {(float*)alloc_b(nP * 4), (float*)alloc_b(nP * 4)};
  float* gbb[2] = {(float*)alloc_b(nP * 4), (float*)alloc_b(nP * 4)};
  float* part = (float*)alloc_b(64 * 4);
  if (ws_size < off) {
    write_val_k<<<1, 1, 0, stream>>>(out, -(float)(ws_size >> 20));
    return;
  }

  // prep
  norm_weights_k<<<BB, 256, 0, stream>>>(W1, aW, la, NPTS);
  norm_weights_k<<<BB, 256, 0, stream>>>(W2, bW, lb, NPTS);
  sqnorm_cvt_k<<<BB * NPTS / 4, 256, 0, stream>>>(X, x2, Xh, BB * NPTS);
  sqnorm_cvt_k<<<BB * NPTS / 4, 256, 0, stream>>>(Y, y2, Yh, BB * NPTS);

  const float LN2 = 0.6931471805599453f;
  const float LOG2E = 1.4426950408889634f;
  dim3 fg(NPTS / BROWS, BB, 4);

  auto launch4 = [&](SMTask A, SMTask B2, SMTask C, SMTask D2, float eps) {
    float ie2 = LOG2E / eps;
    float nel = -eps * LN2;
    fused_softmin_k<<<fg, 256, 0, stream>>>(A, B2, C, D2, ie2, nel);
  };

  // init at eps0 (no potential, no averaging)
  {
    float e = EPS_H[0];
    launch4(
        SMTask{Xh, Yh, lb, nullptr, y2, x2, nullptr, fba[0]},
        SMTask{Yh, Xh, la, nullptr, x2, y2, nullptr, gab[0]},
        SMTask{Xh, Xh, la, nullptr, x2, x2, nullptr, faa[0]},
        SMTask{Yh, Yh, lb, nullptr, y2, y2, nullptr, gbb[0]},
        e);
  }

  // annealing loop: symmetric averaged updates, double-buffered
  int cur = 0;
  for (int it = 0; it < 9; ++it) {
    float e = EPS_H[it];
    int nxt = cur ^ 1;
    launch4(
        SMTask{Xh, Yh, lb, gab[cur], y2, x2, fba[cur], fba[nxt]},
        SMTask{Yh, Xh, la, fba[cur], x2, y2, gab[cur], gab[nxt]},
        SMTask{Xh, Xh, la, faa[cur], x2, x2, faa[cur], faa[nxt]},
        SMTask{Yh, Yh, lb, gbb[cur], y2, y2, gbb[cur], gbb[nxt]},
        e);
    cur = nxt;
  }

  // final extrapolation at eps target (no averaging)
  {
    float e = EPS_H[8];
    int nxt = cur ^ 1;
    launch4(
        SMTask{Xh, Yh, lb, gab[cur], y2, x2, nullptr, fba[nxt]},
        SMTask{Yh, Xh, la, fba[cur], x2, y2, nullptr, gab[nxt]},
        SMTask{Xh, Xh, la, faa[cur], x2, x2, nullptr, faa[nxt]},
        SMTask{Yh, Yh, lb, gbb[cur], y2, y2, nullptr, gbb[nxt]},
        e);
    loss_part_k<<<64, 256, 0, stream>>>(aW, fba[nxt], faa[nxt], bW, gab[nxt],
                                        gbb[nxt], part);
    loss_fin_k<<<1, 64, 0, stream>>>(part, out);
  }
}